// Round 1
// 645.138 us; speedup vs baseline: 1.1243x; 1.1243x over previous
//
#include <hip/hip_runtime.h>

#define B_ 2048
#define D_ 512
#define C_ 50000
#define NTILEN 391            // ceil(50000/128)
#define NPART (NTILEN * 2)    // per-row partials: one per (n-tile, wave-half)
#define PPX 49                // ceil(391 panels / 8 XCDs)

static constexpr float S_SCALE = 15.0f;
static constexpr float COS_M_ = 0.86602540378443864676f;  // cos(pi/6)
static constexpr float SIN_M_ = 0.5f;                     // sin(pi/6)
static constexpr float TH_    = -0.86602540378443864676f; // cos(pi - m)
static constexpr float MM_    = 0.26179938779914943654f;  // sin(pi-m)*m

typedef unsigned short u16;
typedef __attribute__((ext_vector_type(4))) float f32x4;
typedef __attribute__((ext_vector_type(8))) short s16x8;

__device__ __forceinline__ u16 f2bf(float f) {
  unsigned u = __float_as_uint(f);
  u += 0x7fffu + ((u >> 16) & 1u);  // RNE
  return (u16)(u >> 16);
}

__device__ __forceinline__ void load_lds16(const void* g, void* l) {
  __builtin_amdgcn_global_load_lds((const __attribute__((address_space(1))) void*)g,
                                   (__attribute__((address_space(3))) void*)l,
                                   16, 0, 0);
}

// One block (128 threads) per row: L2-normalize, emit bf16.
__global__ void rownorm_kernel(const float* __restrict__ src, u16* __restrict__ dst,
                               float* __restrict__ loss_zero) {
  const int row = blockIdx.x;
  const int tid = threadIdx.x;  // 128 threads, 4 floats each = 512
  const float4* s = (const float4*)(src + (size_t)row * D_);
  float4 v = s[tid];
  float ss = v.x * v.x + v.y * v.y + v.z * v.z + v.w * v.w;
#pragma unroll
  for (int mask = 1; mask < 64; mask <<= 1) ss += __shfl_xor(ss, mask);
  __shared__ float red[2];
  if ((tid & 63) == 0) red[tid >> 6] = ss;
  __syncthreads();
  float total = red[0] + red[1];
  float inv = 1.0f / fmaxf(sqrtf(total), 1e-12f);
  ushort4 o;
  o.x = f2bf(v.x * inv); o.y = f2bf(v.y * inv);
  o.z = f2bf(v.z * inv); o.w = f2bf(v.w * inv);
  ((ushort4*)(dst + (size_t)row * D_))[tid] = o;
  if (loss_zero && row == 0 && tid == 0) *loss_zero = 0.0f;
}

// 128x128 tile, BK=64, 4 waves (2x2), 16x16x32 bf16 MFMA.
// v2: double-buffered LDS 2-phase pipeline (counted vmcnt(8) + raw s_barrier),
//     XCD-chunked panel mapping (each wn panel consumed within one XCD's L2),
//     nontemporal out stores (keep wn resident in L2/L3).
// LDS staged via global_load_lds width=16 with XOR chunk swizzle
// (chunk stored at cs = kc ^ (row&7)) so ds_read_b128 is 2-way (free).
__global__ __launch_bounds__(256) void aam_gemm_kernel(
    const u16* __restrict__ xn, const u16* __restrict__ wn,
    const int* __restrict__ label, float* __restrict__ out,
    float* __restrict__ partial, float* __restrict__ target) {
  __shared__ u16 sA[2][128 * 64];   // 2 x 16 KiB
  __shared__ u16 sB[2][128 * 64];   // 2 x 16 KiB  (total 64 KiB exactly)

  // ---- bijective XCD-chunked mapping --------------------------------------
  // HW round-robins blockIdx -> XCD (bid & 7). Give each XCD whole n-panels:
  // 16 consecutive per-XCD slots = the 16 m-tiles of one panel, so the panel
  // (131 KB of wn) stays in that XCD's L2 for all its readers.
  const int bid = blockIdx.x;
  const int xcd = bid & 7;
  const int slot = bid >> 3;        // 0..783 within this XCD
  const int nt = (slot >> 4) * 8 + xcd;
  if (nt >= NTILEN) return;         // 16 pad blocks (xcd=7, last group)
  const int mt = slot & 15;
  const int m0 = mt * 128;
  const int n0 = nt * 128;

  const int tid = threadIdx.x;
  const int wave = tid >> 6;
  const int lane = tid & 63;
  const int wm = wave >> 1;
  const int wn_ = wave & 1;

  // Labels for this lane's 16 output rows -> registers (LDS is full at 64 KB).
  // 16 lanes per group share an address -> coalesces to broadcast loads.
  int lblr[4][4];
#pragma unroll
  for (int mf = 0; mf < 4; ++mf)
#pragma unroll
    for (int reg = 0; reg < 4; ++reg)
      lblr[mf][reg] = label[m0 + wm * 64 + mf * 16 + ((lane >> 4) << 2) + reg];

  f32x4 acc[4][4];
#pragma unroll
  for (int i = 0; i < 4; ++i)
#pragma unroll
    for (int j = 0; j < 4; ++j) {
      f32x4 z = {0.0f, 0.0f, 0.0f, 0.0f};
      acc[i][j] = z;
    }

  // 8 global_load_lds (wave-level) per thread per tile: 4 A + 4 B.
  auto stage = [&](int kt, int b) {
    const int k0 = kt * 64;
#pragma unroll
    for (int j = 0; j < 4; ++j) {
      const int L = j * 256 + tid;   // 16B chunk index: row m, swizzled col cs
      const int m = L >> 3;
      const int cs = L & 7;
      const int kc = cs ^ (m & 7);
      load_lds16(xn + (size_t)(m0 + m) * D_ + k0 + kc * 8, &sA[b][L * 8]);
    }
#pragma unroll
    for (int j = 0; j < 4; ++j) {
      const int L = j * 256 + tid;
      const int m = L >> 3;
      const int cs = L & 7;
      const int kc = cs ^ (m & 7);
      int wr = n0 + m;
      if (wr >= C_) wr = 0;  // clamp; masked in epilogue
      load_lds16(wn + (size_t)wr * D_ + k0 + kc * 8, &sB[b][L * 8]);
    }
  };

  stage(0, 0);
  int cur = 0;
  for (int kt = 0; kt < D_ / 64; ++kt) {
    if (kt + 1 < D_ / 64) {
      stage(kt + 1, cur ^ 1);                       // issue next tile first
      asm volatile("s_waitcnt vmcnt(8)" ::: "memory");  // oldest 8 = cur tile
    } else {
      asm volatile("s_waitcnt vmcnt(0)" ::: "memory");
    }
    __builtin_amdgcn_s_barrier();                   // raw: no vmcnt(0) drain
    asm volatile("" ::: "memory");

    const u16* __restrict__ A = &sA[cur][0];
    const u16* __restrict__ Bs = &sB[cur][0];
#pragma unroll
    for (int kk = 0; kk < 2; ++kk) {
      const int chunk = kk * 4 + (lane >> 4);
      s16x8 af[4], bf[4];
#pragma unroll
      for (int mf = 0; mf < 4; ++mf) {
        const int r = wm * 64 + mf * 16 + (lane & 15);
        const int cs = chunk ^ (r & 7);
        af[mf] = *(const s16x8*)&A[r * 64 + cs * 8];
      }
#pragma unroll
      for (int nf = 0; nf < 4; ++nf) {
        const int r = wn_ * 64 + nf * 16 + (lane & 15);
        const int cs = chunk ^ (r & 7);
        bf[nf] = *(const s16x8*)&Bs[r * 64 + cs * 8];
      }
#pragma unroll
      for (int mf = 0; mf < 4; ++mf)
#pragma unroll
        for (int nf = 0; nf < 4; ++nf)
          acc[mf][nf] = __builtin_amdgcn_mfma_f32_16x16x32_bf16(af[mf], bf[nf],
                                                                acc[mf][nf], 0, 0, 0);
    }
    asm volatile("s_waitcnt lgkmcnt(0)" ::: "memory");  // ds_reads done before
    __builtin_amdgcn_s_barrier();                        // buffer is re-staged
    asm volatile("" ::: "memory");
    cur ^= 1;
  }

  // Epilogue: margin fixup + store + per-(row, 64-col-slab) softmax partials.
  // C/D layout: col = lane&15, row = (lane>>4)*4 + reg  [learn_hip m89]
  const int colbase = n0 + wn_ * 64 + (lane & 15);
#pragma unroll
  for (int mf = 0; mf < 4; ++mf) {
#pragma unroll
    for (int reg = 0; reg < 4; ++reg) {
      const int row_l = wm * 64 + mf * 16 + ((lane >> 4) << 2) + reg;
      const int row_g = m0 + row_l;
      const int lbl = lblr[mf][reg];
      float v[4];
      float vmax = -INFINITY;
#pragma unroll
      for (int nf = 0; nf < 4; ++nf) {
        const int col = colbase + nf * 16;
        float cv = acc[mf][nf][reg];
        float val = S_SCALE * cv;
        if (col == lbl) {
          float st = sqrtf(fminf(fmaxf(1.0f - cv * cv, 0.0f), 1.0f));
          float phi = cv * COS_M_ - st * SIN_M_;
          float pv = (cv - TH_ > 0.0f) ? phi : (cv - MM_);
          val = S_SCALE * pv;
          target[row_g] = val;
        }
        if (col < C_) {
          // nontemporal: out is write-once, never re-read; keep it out of
          // L2/L3 so wn panels stay resident.
          __builtin_nontemporal_store(val, &out[(size_t)row_g * C_ + col]);
          v[nf] = val;
          vmax = fmaxf(vmax, val);
        } else {
          v[nf] = -INFINITY;
        }
      }
#pragma unroll
      for (int mask = 1; mask < 16; mask <<= 1)
        vmax = fmaxf(vmax, __shfl_xor(vmax, mask));
      float sev = 0.0f;
#pragma unroll
      for (int nf = 0; nf < 4; ++nf)
        if (v[nf] != -INFINITY) sev += __expf(v[nf] - vmax);
#pragma unroll
      for (int mask = 1; mask < 16; mask <<= 1) sev += __shfl_xor(sev, mask);
      if ((lane & 15) == 0) {
        float* p = partial + ((size_t)row_g * NPART + (nt * 2 + wn_)) * 2;
        p[0] = vmax;
        p[1] = sev;
      }
    }
  }
}

// One wave per row: merge 782 (max,sumexp) partials -> lse; loss = mean(lse - tgt).
__global__ __launch_bounds__(256) void loss_kernel(const float* __restrict__ partial,
                                                   const float* __restrict__ target,
                                                   float* __restrict__ loss) {
  const int lane = threadIdx.x & 63;
  const int row = blockIdx.x * 4 + (threadIdx.x >> 6);
  float m = -INFINITY, l = 0.0f;
  const float2* p = (const float2*)partial + (size_t)row * NPART;
  for (int i = lane; i < NPART; i += 64) {
    float2 q = p[i];
    if (q.x > m) {
      l = l * __expf(m - q.x) + q.y;
      m = q.x;
    } else if (q.x != -INFINITY) {
      l += q.y * __expf(q.x - m);
    }
  }
#pragma unroll
  for (int mask = 1; mask < 64; mask <<= 1) {
    float m2 = __shfl_xor(m, mask);
    float l2 = __shfl_xor(l, mask);
    if (m2 > m) {
      l = l * __expf(m - m2) + l2;
      m = m2;
    } else if (m2 != -INFINITY) {
      l += l2 * __expf(m2 - m);
    }
  }
  __shared__ float sred[4];
  if (lane == 0) sred[threadIdx.x >> 6] = (m + logf(l)) - target[row];
  __syncthreads();
  if (threadIdx.x == 0)
    atomicAdd(loss, (sred[0] + sred[1] + sred[2] + sred[3]) * (1.0f / 2048.0f));
}

extern "C" void kernel_launch(void* const* d_in, const int* in_sizes, int n_in,
                              void* d_out, int out_size, void* d_ws, size_t ws_size,
                              hipStream_t stream) {
  const float* x = (const float*)d_in[0];
  const int* label = (const int*)d_in[1];
  const float* w = (const float*)d_in[2];
  float* out = (float*)d_out;
  float* loss = out + (size_t)B_ * C_;  // last element of d_out

  // workspace layout (~66.1 MB total)
  u16* xn = (u16*)d_ws;                              //  2.10 MB
  u16* wn = xn + (size_t)B_ * D_;                    // 51.20 MB
  float* partial = (float*)(wn + (size_t)C_ * D_);   // 12.81 MB
  float* target = partial + (size_t)B_ * NPART * 2;  //  8 KB

  rownorm_kernel<<<B_, 128, 0, stream>>>(x, xn, loss);       // also zeroes loss
  rownorm_kernel<<<C_, 128, 0, stream>>>(w, wn, nullptr);
  aam_gemm_kernel<<<8 * PPX * 16, 256, 0, stream>>>(xn, wn, label, out, partial, target);
  loss_kernel<<<B_ / 4, 256, 0, stream>>>(partial, target, loss);
}